// Round 3
// baseline (1036.389 us; speedup 1.0000x reference)
//
#include <hip/hip_runtime.h>
#include <math.h>

#define NBINS 255
#define BIN_LO_F (-20.0f)
#define BIN_HI_F (20.0f)

typedef __attribute__((ext_vector_type(8))) short short8;
typedef __attribute__((ext_vector_type(16))) float f32x16;

__device__ __forceinline__ unsigned short f2bf(float f) {
    unsigned u = __builtin_bit_cast(unsigned, f);
    unsigned r = u + 0x7fffu + ((u >> 16) & 1u);
    return (unsigned short)(r >> 16);
}

__device__ __forceinline__ double wave_reduce_sum_d(double v) {
    #pragma unroll
    for (int m = 32; m >= 1; m >>= 1) v += __shfl_xor(v, m, 64);
    return v;
}

// Pack W (D,255) fp32 -> bf16, layout: flat short8 index t = kstep*2048 + sub8*256 + col,
// element e -> k = kstep*64 + sub8*8 + e, col 255 is zero pad.
__global__ __launch_bounds__(256) void pack_w(
    const float* __restrict__ W, char* __restrict__ Wpack)
{
    int t = blockIdx.x * 256 + threadIdx.x;
    int col = t & 255;
    int k0 = ((t >> 11) << 6) + (((t >> 8) & 7) << 3);
    short8 s;
    #pragma unroll
    for (int e = 0; e < 8; ++e)
        s[e] = (col < NBINS) ? (short)f2bf(W[(size_t)(k0 + e) * NBINS + col]) : (short)0;
    *(short8*)(Wpack + (size_t)t * 16) = s;
}

// Barrier-free MFMA GEMM. Block = 512 threads = 8 waves: wave = rowgroup (2) x k-quarter (4).
// Each wave: 32 rows x 256 cols x K/4, acc 8 x f32x16. A: per-lane global fp32 -> f2bf.
// B: per-lane 16B coalesced loads from L2-resident Wpack. 1-deep reg pipeline, no syncs
// in the main loop. Epilogue: LDS combine of 4 K-partials (fixed order), bias, store.
__global__ __launch_bounds__(512, 1) void gemm_mfma_v2(
    const float* __restrict__ latents, const float* __restrict__ boot,
    const char* __restrict__ Wpack, const float* __restrict__ bvec,
    float* __restrict__ logits, int NR, int R, int D)
{
    __shared__ float cb[2][3][1024];   // 24 KB epilogue combine buffer

    const int tid  = threadIdx.x;
    const int wave = tid >> 6, lane = tid & 63;
    const int l31  = lane & 31, lhi = lane >> 5;
    const int rg   = wave & 1;         // rowgroup within block
    const int kq   = wave >> 1;        // k-quarter 0..3
    const int row0 = blockIdx.x * 64 + rg * 32;
    const int KQ   = D >> 2;           // 1024
    const int NC   = KQ >> 4;          // 64 chunks of 16 k
    const int k0   = kq * KQ;

    // A: this lane streams row (row0+l31), k-half lhi
    int rowg = row0 + l31; if (rowg > R - 1) rowg = R - 1;
    const float* aptr = (rowg < NR) ? latents + (size_t)rowg * D
                                    : boot + (size_t)(rowg - NR) * D;
    aptr += k0 + lhi * 8;

    f32x16 acc[8];
    #pragma unroll
    for (int g = 0; g < 8; ++g)
        #pragma unroll
        for (int r = 0; r < 16; ++r) acc[g][r] = 0.f;

    // B byte offset for chunk c, group g:
    //   ((k0>>6)+(c>>2))*32768 + (((2c)&7)+lhi)*4096 + g*512 + l31*16
    const size_t bfix = (size_t)(k0 >> 6) * 32768 + (size_t)lhi * 4096 + (size_t)l31 * 16;

    float4 Af[2][2];
    short8 Bf[2][8];

    // prime chunk 0
    Af[0][0] = *(const float4*)(aptr);
    Af[0][1] = *(const float4*)(aptr + 4);
    {
        const char* bb = Wpack + bfix;
        #pragma unroll
        for (int g = 0; g < 8; ++g) Bf[0][g] = *(const short8*)(bb + g * 512);
    }

    #pragma unroll 2
    for (int c = 0; c < NC; ++c) {
        const int cur = c & 1, nxt = cur ^ 1;
        if (c + 1 < NC) {
            const float* ap = aptr + (c + 1) * 16;
            Af[nxt][0] = *(const float4*)(ap);
            Af[nxt][1] = *(const float4*)(ap + 4);
            const char* bb = Wpack + bfix + (size_t)((c + 1) >> 2) * 32768
                                         + (size_t)((2 * (c + 1)) & 7) * 4096;
            #pragma unroll
            for (int g = 0; g < 8; ++g) Bf[nxt][g] = *(const short8*)(bb + g * 512);
        }
        short8 a;
        #pragma unroll
        for (int e = 0; e < 4; ++e) {
            a[e]     = (short)f2bf(Af[cur][0][e]);
            a[4 + e] = (short)f2bf(Af[cur][1][e]);
        }
        #pragma unroll
        for (int g = 0; g < 8; ++g)
            acc[g] = __builtin_amdgcn_mfma_f32_32x32x16_bf16(a, Bf[cur][g], acc[g], 0, 0, 0);
    }

    // ---- epilogue: combine 4 K-partials per rowgroup (fixed add order) ----
    #pragma unroll
    for (int rr = 0; rr < 8; ++rr) {
        __syncthreads();
        if (kq > 0) {
            #pragma unroll
            for (int e = 0; e < 16; ++e) cb[rg][kq - 1][e * 64 + lane] = acc[rr][e];
        }
        __syncthreads();
        if (kq == 0) {
            #pragma unroll
            for (int e = 0; e < 16; ++e)
                acc[rr][e] += cb[rg][0][e * 64 + lane]
                            + cb[rg][1][e * 64 + lane]
                            + cb[rg][2][e * 64 + lane];
        }
    }

    if (kq == 0) {
        #pragma unroll
        for (int g = 0; g < 8; ++g) {
            int col = g * 32 + l31;
            if (col < NBINS) {
                float bias = bvec[col];
                #pragma unroll
                for (int r = 0; r < 16; ++r) {
                    int row = row0 + (r & 3) + 8 * (r >> 2) + 4 * lhi;
                    if (row < R) logits[(size_t)row * NBINS + col] = acc[g][r] + bias;
                }
            }
        }
    }
}

// per-row softmax stats: value = softmax(l)@centers, logZ
__global__ __launch_bounds__(256) void softmax_stats(
    const float* __restrict__ logits, float* __restrict__ values,
    float* __restrict__ logZ, int R)
{
    int row  = blockIdx.x * 4 + (threadIdx.x >> 6);
    int lane = threadIdx.x & 63;
    if (row >= R) return;
    const float* lp = logits + (size_t)row * NBINS;
    const float step = (float)(40.0 / 254.0);

    float l[4];
    float m = -INFINITY;
    #pragma unroll
    for (int u = 0; u < 4; ++u) {
        int idx = lane + 64 * u;
        l[u] = (idx < NBINS) ? lp[idx] : -INFINITY;
        m = fmaxf(m, l[u]);
    }
    #pragma unroll
    for (int sh = 32; sh >= 1; sh >>= 1) m = fmaxf(m, __shfl_xor(m, sh, 64));

    float s = 0.f, sc = 0.f;
    #pragma unroll
    for (int u = 0; u < 4; ++u) {
        int idx = lane + 64 * u;
        if (idx < NBINS) {
            float e = __expf(l[u] - m);
            s  += e;
            sc += e * (BIN_LO_F + step * (float)idx);
        }
    }
    #pragma unroll
    for (int sh = 32; sh >= 1; sh >>= 1) {
        s  += __shfl_xor(s, sh, 64);
        sc += __shfl_xor(sc, sh, 64);
    }
    if (lane == 0) {
        values[row] = sc / s;
        logZ[row]   = m + __logf(s);
    }
}

__global__ void lambda_returns_k(
    const float* __restrict__ rewards, const float* __restrict__ dones,
    const float* __restrict__ values, float* __restrict__ returns,
    int B, int H, int NR)
{
    int b = blockIdx.x * blockDim.x + threadIdx.x;
    if (b >= B) return;
    const float gamma = 0.997f;
    const float lam   = 0.95f;
    const float oml   = (float)(1.0 - 0.95);
    float bootv = values[NR + b];
    float g = bootv;
    for (int h = H - 1; h >= 0; --h) {
        float nv   = (h == H - 1) ? bootv : values[b * H + h + 1];
        float mask = 1.0f - dones[b * H + h];
        g = rewards[b * H + h] + gamma * mask * (oml * nv + lam * g);
        returns[b * H + h] = g;
    }
}

__global__ __launch_bounds__(256) void loss_moments(
    const float* __restrict__ logits, const float* __restrict__ logZ,
    const float* __restrict__ values, const float* __restrict__ returns,
    double* __restrict__ accum, int NR)
{
    int row = blockIdx.x * blockDim.x + threadIdx.x;
    double lsum = 0, vsum = 0, v2 = 0, rsum = 0, r2 = 0;
    if (row < NR) {
        float v   = values[row];
        float ret = returns[row];
        float cl  = fminf(fmaxf(ret, BIN_LO_F), BIN_HI_F);
        const float step = (float)(40.0 / 254.0);
        float pos = (cl - BIN_LO_F) / step;
        int low = (int)floorf(pos);
        low = min(max(low, 0), NBINS - 2);
        float frac = pos - (float)low;
        const float* lp = logits + (size_t)row * NBINS;
        float llo = lp[low], lhi = lp[low + 1];
        float loss = logZ[row] - (1.f - frac) * llo - frac * lhi;
        lsum = (double)loss;
        vsum = (double)v;   v2 = (double)v * (double)v;
        rsum = (double)ret; r2 = (double)ret * (double)ret;
    }
    lsum = wave_reduce_sum_d(lsum);
    vsum = wave_reduce_sum_d(vsum);
    v2   = wave_reduce_sum_d(v2);
    rsum = wave_reduce_sum_d(rsum);
    r2   = wave_reduce_sum_d(r2);
    if ((threadIdx.x & 63) == 0) {
        atomicAdd(&accum[0], lsum);
        atomicAdd(&accum[1], vsum);
        atomicAdd(&accum[2], v2);
        atomicAdd(&accum[3], rsum);
        atomicAdd(&accum[4], r2);
    }
}

__global__ void finalize_k(const double* __restrict__ accum,
                           float* __restrict__ out, int NR)
{
    if (threadIdx.x == 0 && blockIdx.x == 0) {
        double n  = (double)NR;
        double vl = accum[0] / n;
        double mv = accum[1] / n;
        double vv = (accum[2] - n * mv * mv) / (n - 1.0);
        double mr = accum[3] / n;
        double vr = (accum[4] - n * mr * mr) / (n - 1.0);
        out[0] = (float)(0.5 * vl);
        out[1] = (float)vl;
        out[2] = (float)mv;
        out[3] = (float)mr;
        out[4] = (float)sqrt(vv > 0.0 ? vv : 0.0);
        out[5] = (float)sqrt(vr > 0.0 ? vr : 0.0);
    }
}

extern "C" void kernel_launch(void* const* d_in, const int* in_sizes, int n_in,
                              void* d_out, int out_size, void* d_ws, size_t ws_size,
                              hipStream_t stream) {
    const float* latents = (const float*)d_in[0];
    const float* rewards = (const float*)d_in[1];
    const float* dones   = (const float*)d_in[2];
    const float* boot    = (const float*)d_in[3];
    const float* W       = (const float*)d_in[4];
    const float* bvec    = (const float*)d_in[5];
    float* out = (float*)d_out;

    const int BH = in_sizes[1];          // B*H = 16384
    const int D  = in_sizes[0] / BH;     // 4096
    const int B  = in_sizes[3] / D;      // 1024
    const int H  = BH / B;               // 16
    const int NR = BH;
    const int R  = NR + B;               // 17408

    char* ws = (char*)d_ws;
    size_t off = 0;
    float* logits = (float*)(ws + off); off += (size_t)R * NBINS * sizeof(float);
    off = (off + 255) & ~(size_t)255;
    float* values = (float*)(ws + off); off += (size_t)R * sizeof(float);
    float* logZ   = (float*)(ws + off); off += (size_t)R * sizeof(float);
    float* rets   = (float*)(ws + off); off += (size_t)NR * sizeof(float);
    off = (off + 255) & ~(size_t)255;
    double* accum = (double*)(ws + off); off += 64;
    off = (off + 255) & ~(size_t)255;
    char* Wpack   = ws + off; off += (size_t)(D / 64) * 32768;

    hipMemsetAsync(accum, 0, 64, stream);

    const int packThreads = (D / 64) * 8 * 256;     // one short8 per thread
    pack_w<<<packThreads / 256, 256, 0, stream>>>(W, Wpack);
    gemm_mfma_v2<<<R / 64, 512, 0, stream>>>(latents, boot, Wpack, bvec, logits, NR, R, D);
    softmax_stats<<<(R + 3) / 4, 256, 0, stream>>>(logits, values, logZ, R);
    lambda_returns_k<<<(B + 255) / 256, 256, 0, stream>>>(rewards, dones, values, rets, B, H, NR);
    loss_moments<<<(NR + 255) / 256, 256, 0, stream>>>(logits, logZ, values, rets, accum, NR);
    finalize_k<<<1, 64, 0, stream>>>(accum, out, NR);
}

// Round 4
// 261.183 us; speedup vs baseline: 3.9681x; 3.9681x over previous
//
#include <hip/hip_runtime.h>
#include <math.h>

#define NBINS 255
#define BIN_LO_F (-20.0f)
#define BIN_HI_F (20.0f)

typedef __attribute__((ext_vector_type(8))) short short8;
typedef __attribute__((ext_vector_type(16))) float f32x16;

__device__ __forceinline__ unsigned short f2bf(float f) {
    unsigned u = __builtin_bit_cast(unsigned, f);
    unsigned r = u + 0x7fffu + ((u >> 16) & 1u);
    return (unsigned short)(r >> 16);
}

__device__ __forceinline__ double wave_reduce_sum_d(double v) {
    #pragma unroll
    for (int m = 32; m >= 1; m >>= 1) v += __shfl_xor(v, m, 64);
    return v;
}

// Pack W (D,255) fp32 -> bf16, layout: flat short8 index t = kstep*2048 + sub8*256 + col,
// element e -> k = kstep*64 + sub8*8 + e, col 255 is zero pad.
__global__ __launch_bounds__(256) void pack_w(
    const float* __restrict__ W, char* __restrict__ Wpack)
{
    int t = blockIdx.x * 256 + threadIdx.x;
    int col = t & 255;
    int k0 = ((t >> 11) << 6) + (((t >> 8) & 7) << 3);
    short8 s;
    #pragma unroll
    for (int e = 0; e < 8; ++e)
        s[e] = (col < NBINS) ? (short)f2bf(W[(size_t)(k0 + e) * NBINS + col]) : (short)0;
    *(short8*)(Wpack + (size_t)t * 16) = s;
}

// Barrier-free MFMA GEMM, STATIC register pipeline (rule #20: no runtime-indexed
// ext_vector arrays). Block = 512 threads = 8 waves: wave = rowgroup(2) x k-quarter(4).
// Each wave: 32 rows x 256 cols x K/4, acc 8 x f32x16 (AGPR). A: per-lane global fp32
// -> f2bf. B: per-lane 16B loads from L2/L3-resident Wpack; chunk c offset = bfix + c*8192.
__global__ __launch_bounds__(512, 1) void gemm_mfma_v3(
    const float* __restrict__ latents, const float* __restrict__ boot,
    const char* __restrict__ Wpack, const float* __restrict__ bvec,
    float* __restrict__ logits, int NR, int R, int D)
{
    __shared__ float cb[2][3][1024];   // 24 KB epilogue combine buffer

    const int tid  = threadIdx.x;
    const int wave = tid >> 6, lane = tid & 63;
    const int l31  = lane & 31, lhi = lane >> 5;
    const int rg   = wave & 1;         // rowgroup within block
    const int kq   = wave >> 1;        // k-quarter 0..3
    const int row0 = blockIdx.x * 64 + rg * 32;
    const int KQ   = D >> 2;           // 1024
    const int NC   = KQ >> 4;          // 64 chunks of 16 k
    const int k0   = kq * KQ;

    // A: this lane streams row (row0+l31), k-half lhi
    int rowg = row0 + l31; if (rowg > R - 1) rowg = R - 1;
    const float* aptr = (rowg < NR) ? latents + (size_t)rowg * D
                                    : boot + (size_t)(rowg - NR) * D;
    aptr += k0 + lhi * 8;

    f32x16 acc[8];
    #pragma unroll
    for (int g = 0; g < 8; ++g)
        #pragma unroll
        for (int r = 0; r < 16; ++r) acc[g][r] = 0.f;

    const char* bptr = Wpack + (size_t)(k0 >> 6) * 32768 + (size_t)lhi * 4096
                             + (size_t)l31 * 16;

    float4 Aa0, Aa1, Ab0, Ab1;
    short8 Ba[8], Bb[8];

    // prime chunk 0
    Aa0 = *(const float4*)(aptr);
    Aa1 = *(const float4*)(aptr + 4);
    #pragma unroll
    for (int g = 0; g < 8; ++g) Ba[g] = *(const short8*)(bptr + g * 512);

    for (int c = 0; c < NC; c += 2) {
        // prefetch chunk c+1 (NC even -> always valid)
        {
            const float* ap = aptr + (size_t)(c + 1) * 16;
            Ab0 = *(const float4*)(ap);
            Ab1 = *(const float4*)(ap + 4);
            const char* bp = bptr + (size_t)(c + 1) * 8192;
            #pragma unroll
            for (int g = 0; g < 8; ++g) Bb[g] = *(const short8*)(bp + g * 512);
        }
        // compute chunk c
        {
            short8 a;
            #pragma unroll
            for (int e = 0; e < 4; ++e) {
                a[e]     = (short)f2bf(Aa0[e]);
                a[4 + e] = (short)f2bf(Aa1[e]);
            }
            #pragma unroll
            for (int g = 0; g < 8; ++g)
                acc[g] = __builtin_amdgcn_mfma_f32_32x32x16_bf16(a, Ba[g], acc[g], 0, 0, 0);
        }
        // prefetch chunk c+2
        if (c + 2 < NC) {
            const float* ap = aptr + (size_t)(c + 2) * 16;
            Aa0 = *(const float4*)(ap);
            Aa1 = *(const float4*)(ap + 4);
            const char* bp = bptr + (size_t)(c + 2) * 8192;
            #pragma unroll
            for (int g = 0; g < 8; ++g) Ba[g] = *(const short8*)(bp + g * 512);
        }
        // compute chunk c+1
        {
            short8 a;
            #pragma unroll
            for (int e = 0; e < 4; ++e) {
                a[e]     = (short)f2bf(Ab0[e]);
                a[4 + e] = (short)f2bf(Ab1[e]);
            }
            #pragma unroll
            for (int g = 0; g < 8; ++g)
                acc[g] = __builtin_amdgcn_mfma_f32_32x32x16_bf16(a, Bb[g], acc[g], 0, 0, 0);
        }
    }

    // ---- epilogue: combine 4 K-partials per rowgroup (fixed add order) ----
    #pragma unroll
    for (int rr = 0; rr < 8; ++rr) {
        __syncthreads();
        if (kq > 0) {
            #pragma unroll
            for (int e = 0; e < 16; ++e) cb[rg][kq - 1][e * 64 + lane] = acc[rr][e];
        }
        __syncthreads();
        if (kq == 0) {
            #pragma unroll
            for (int e = 0; e < 16; ++e)
                acc[rr][e] += cb[rg][0][e * 64 + lane]
                            + cb[rg][1][e * 64 + lane]
                            + cb[rg][2][e * 64 + lane];
        }
    }

    if (kq == 0) {
        #pragma unroll
        for (int g = 0; g < 8; ++g) {
            int col = g * 32 + l31;
            if (col < NBINS) {
                float bias = bvec[col];
                #pragma unroll
                for (int r = 0; r < 16; ++r) {
                    int row = row0 + (r & 3) + 8 * (r >> 2) + 4 * lhi;
                    if (row < R) logits[(size_t)row * NBINS + col] = acc[g][r] + bias;
                }
            }
        }
    }
}

// per-row softmax stats: value = softmax(l)@centers, logZ
__global__ __launch_bounds__(256) void softmax_stats(
    const float* __restrict__ logits, float* __restrict__ values,
    float* __restrict__ logZ, int R)
{
    int row  = blockIdx.x * 4 + (threadIdx.x >> 6);
    int lane = threadIdx.x & 63;
    if (row >= R) return;
    const float* lp = logits + (size_t)row * NBINS;
    const float step = (float)(40.0 / 254.0);

    float l[4];
    float m = -INFINITY;
    #pragma unroll
    for (int u = 0; u < 4; ++u) {
        int idx = lane + 64 * u;
        l[u] = (idx < NBINS) ? lp[idx] : -INFINITY;
        m = fmaxf(m, l[u]);
    }
    #pragma unroll
    for (int sh = 32; sh >= 1; sh >>= 1) m = fmaxf(m, __shfl_xor(m, sh, 64));

    float s = 0.f, sc = 0.f;
    #pragma unroll
    for (int u = 0; u < 4; ++u) {
        int idx = lane + 64 * u;
        if (idx < NBINS) {
            float e = __expf(l[u] - m);
            s  += e;
            sc += e * (BIN_LO_F + step * (float)idx);
        }
    }
    #pragma unroll
    for (int sh = 32; sh >= 1; sh >>= 1) {
        s  += __shfl_xor(s, sh, 64);
        sc += __shfl_xor(sc, sh, 64);
    }
    if (lane == 0) {
        values[row] = sc / s;
        logZ[row]   = m + __logf(s);
    }
}

__global__ void lambda_returns_k(
    const float* __restrict__ rewards, const float* __restrict__ dones,
    const float* __restrict__ values, float* __restrict__ returns,
    int B, int H, int NR)
{
    int b = blockIdx.x * blockDim.x + threadIdx.x;
    if (b >= B) return;
    const float gamma = 0.997f;
    const float lam   = 0.95f;
    const float oml   = (float)(1.0 - 0.95);
    float bootv = values[NR + b];
    float g = bootv;
    for (int h = H - 1; h >= 0; --h) {
        float nv   = (h == H - 1) ? bootv : values[b * H + h + 1];
        float mask = 1.0f - dones[b * H + h];
        g = rewards[b * H + h] + gamma * mask * (oml * nv + lam * g);
        returns[b * H + h] = g;
    }
}

__global__ __launch_bounds__(256) void loss_moments(
    const float* __restrict__ logits, const float* __restrict__ logZ,
    const float* __restrict__ values, const float* __restrict__ returns,
    double* __restrict__ accum, int NR)
{
    int row = blockIdx.x * blockDim.x + threadIdx.x;
    double lsum = 0, vsum = 0, v2 = 0, rsum = 0, r2 = 0;
    if (row < NR) {
        float v   = values[row];
        float ret = returns[row];
        float cl  = fminf(fmaxf(ret, BIN_LO_F), BIN_HI_F);
        const float step = (float)(40.0 / 254.0);
        float pos = (cl - BIN_LO_F) / step;
        int low = (int)floorf(pos);
        low = min(max(low, 0), NBINS - 2);
        float frac = pos - (float)low;
        const float* lp = logits + (size_t)row * NBINS;
        float llo = lp[low], lhi = lp[low + 1];
        float loss = logZ[row] - (1.f - frac) * llo - frac * lhi;
        lsum = (double)loss;
        vsum = (double)v;   v2 = (double)v * (double)v;
        rsum = (double)ret; r2 = (double)ret * (double)ret;
    }
    lsum = wave_reduce_sum_d(lsum);
    vsum = wave_reduce_sum_d(vsum);
    v2   = wave_reduce_sum_d(v2);
    rsum = wave_reduce_sum_d(rsum);
    r2   = wave_reduce_sum_d(r2);
    if ((threadIdx.x & 63) == 0) {
        atomicAdd(&accum[0], lsum);
        atomicAdd(&accum[1], vsum);
        atomicAdd(&accum[2], v2);
        atomicAdd(&accum[3], rsum);
        atomicAdd(&accum[4], r2);
    }
}

__global__ void finalize_k(const double* __restrict__ accum,
                           float* __restrict__ out, int NR)
{
    if (threadIdx.x == 0 && blockIdx.x == 0) {
        double n  = (double)NR;
        double vl = accum[0] / n;
        double mv = accum[1] / n;
        double vv = (accum[2] - n * mv * mv) / (n - 1.0);
        double mr = accum[3] / n;
        double vr = (accum[4] - n * mr * mr) / (n - 1.0);
        out[0] = (float)(0.5 * vl);
        out[1] = (float)vl;
        out[2] = (float)mv;
        out[3] = (float)mr;
        out[4] = (float)sqrt(vv > 0.0 ? vv : 0.0);
        out[5] = (float)sqrt(vr > 0.0 ? vr : 0.0);
    }
}

extern "C" void kernel_launch(void* const* d_in, const int* in_sizes, int n_in,
                              void* d_out, int out_size, void* d_ws, size_t ws_size,
                              hipStream_t stream) {
    const float* latents = (const float*)d_in[0];
    const float* rewards = (const float*)d_in[1];
    const float* dones   = (const float*)d_in[2];
    const float* boot    = (const float*)d_in[3];
    const float* W       = (const float*)d_in[4];
    const float* bvec    = (const float*)d_in[5];
    float* out = (float*)d_out;

    const int BH = in_sizes[1];          // B*H = 16384
    const int D  = in_sizes[0] / BH;     // 4096
    const int B  = in_sizes[3] / D;      // 1024
    const int H  = BH / B;               // 16
    const int NR = BH;
    const int R  = NR + B;               // 17408

    char* ws = (char*)d_ws;
    size_t off = 0;
    float* logits = (float*)(ws + off); off += (size_t)R * NBINS * sizeof(float);
    off = (off + 255) & ~(size_t)255;
    float* values = (float*)(ws + off); off += (size_t)R * sizeof(float);
    float* logZ   = (float*)(ws + off); off += (size_t)R * sizeof(float);
    float* rets   = (float*)(ws + off); off += (size_t)NR * sizeof(float);
    off = (off + 255) & ~(size_t)255;
    double* accum = (double*)(ws + off); off += 64;
    off = (off + 255) & ~(size_t)255;
    char* Wpack   = ws + off; off += (size_t)(D / 64) * 32768;

    hipMemsetAsync(accum, 0, 64, stream);

    const int packThreads = (D / 64) * 8 * 256;     // one short8 per thread
    pack_w<<<packThreads / 256, 256, 0, stream>>>(W, Wpack);
    gemm_mfma_v3<<<R / 64, 512, 0, stream>>>(latents, boot, Wpack, bvec, logits, NR, R, D);
    softmax_stats<<<(R + 3) / 4, 256, 0, stream>>>(logits, values, logZ, R);
    lambda_returns_k<<<(B + 255) / 256, 256, 0, stream>>>(rewards, dones, values, rets, B, H, NR);
    loss_moments<<<(NR + 255) / 256, 256, 0, stream>>>(logits, logZ, values, rets, accum, NR);
    finalize_k<<<1, 64, 0, stream>>>(accum, out, NR);
}